// Round 14
// baseline (89.575 us; speedup 1.0000x reference)
//
#include <hip/hip_runtime.h>

#define HID 768
#define NL  17
#define BB  64
#define TT  512

// ---- CRF scan geometry (unchanged from R12) ----
#define SEG  16
#define SLEN 32
#define QST  352

// ===========================================================================
// Kernel 1: emissions = outputs @ fc_w^T + fc_b   (32768x768 @ 768^T x 17)
// R13 ablation: bottleneck is global->LDS delivery, not LDS/VALU issue.
// Fix: NO LDS, NO barriers, NO software pipeline — max occupancy supplies
// the MLP (Little: 6.3 TB/s needs ~9KB in flight/CU = 1 load per 2 waves at
// 32 waves/CU). Wave = 4 rows x 16 lanes: lane (r,c) streams x[row, 64i+4c]
// (4x256B coalesced per instr, 16B/lane), w from L1/L2 as lane-shared float4
// (52KB, L2-resident). 17 acc chains; K-reduce = 4 shfl_xor steps in-reg;
// c==0 lanes store 17 floats. 8192 waves = 32/CU. VGPR ~95 (rolled i-loop).
// ===========================================================================
__global__ __launch_bounds__(256) void emis_kernel(const float* __restrict__ x,
                                                   const float* __restrict__ w,
                                                   const float* __restrict__ bias,
                                                   float* __restrict__ y) {
    const int tid  = threadIdx.x;
    const int lane = tid & 63;
    const int r    = lane >> 4;                // row within wave quad
    const int c    = lane & 15;                // col slot
    const int row  = blockIdx.x * 16 + ((tid >> 6) << 2) + r;

    const float* xp = x + (size_t)row * HID + (c << 2);
    const float* wp = w + (c << 2);

    float acc[NL];
#pragma unroll
    for (int k = 0; k < NL; ++k) acc[k] = 0.f;

#pragma unroll 1
    for (int i = 0; i < 12; ++i) {
        const float4 xv = *reinterpret_cast<const float4*>(xp + 64 * i);
#pragma unroll
        for (int k = 0; k < NL; ++k) {
            const float4 wv = *reinterpret_cast<const float4*>(wp + k * HID + 64 * i);
            float s0 = fmaf(xv.x, wv.x, acc[k]);
            float s1 = xv.y * wv.y;
            s0 = fmaf(xv.z, wv.z, s0);
            s1 = fmaf(xv.w, wv.w, s1);
            acc[k] = s0 + s1;
        }
    }

    // reduce over the 16 c-lanes (stays within each 16-lane group)
#pragma unroll
    for (int k = 0; k < NL; ++k) {
        float v = acc[k];
        v += __shfl_xor(v, 1);
        v += __shfl_xor(v, 2);
        v += __shfl_xor(v, 4);
        v += __shfl_xor(v, 8);
        acc[k] = v;
    }

    if (c == 0) {
        float* yp = y + (size_t)row * NL;
#pragma unroll
        for (int k = 0; k < NL; ++k) yp[k] = acc[k] + bias[k];
    }
}

// ===========================================================================
// Kernel 2a: CRF segment scan — UNCHANGED from R12.
// ===========================================================================
__global__ __launch_bounds__(64) void crf_scan_kernel(const float* __restrict__ emis,
                                                      const float* __restrict__ tr_,
                                                      const int* __restrict__ mask,
                                                      float* __restrict__ ws) {
    __shared__ float QT[2][18][20];

    const int bs = blockIdx.x;
    const int b  = bs >> 4;
    const int s  = bs & 15;
    const int l  = threadIdx.x;
    const float* eb = emis + (size_t)b * TT * NL;

    int lenp = 0;
#pragma unroll
    for (int m = 0; m < 8; ++m) lenp += (mask[b * TT + l + 64 * m] != 0);
#pragma unroll
    for (int off = 32; off; off >>= 1) lenp += __shfl_down(lenp, off);
    const int len = __shfl(lenp, 0);

    const int t0    = 1 + SLEN * s;
    const int tend  = min(t0 + SLEN, len);
    const int trips = (tend > t0) ? (tend - t0) : 0;

    const bool act = (l < 51);
    const int  i   = act ? (l / 3) : 0;
    const int  m   = act ? (l - 3 * (l / 3)) : 0;
    const int  j0  = 6 * m;

    if (act) {
#pragma unroll
        for (int jj = 0; jj < 6; ++jj)
            QT[0][j0 + jj][i] = (i == j0 + jj) ? 1.f : 0.f;
    }

    float at[17];
#pragma unroll
    for (int k = 0; k < 17; ++k) at[k] = __expf(tr_[k * NL + i]);

    float psc = 1.f;
    int   Mi  = 0;
    float emv = (trips > 0) ? eb[t0 * NL + i] : 0.f;
    int   t   = t0;

#define QSTEP(SRC, DST, TCUR)                                                 \
    {                                                                         \
        const float e_ = __expf(emv) * psc;  psc = 1.f;                       \
        const int tn_ = ((TCUR) + 1 < tend) ? ((TCUR) + 1) : (TT - 1);        \
        const float env_ = eb[tn_ * NL + i];                                  \
        float o[6];                                                           \
        _Pragma("unroll")                                                     \
        for (int jj = 0; jj < 6; ++jj) {                                      \
            const float* qr = &QT[SRC][j0 + jj][0];                           \
            const float4 a0 = *reinterpret_cast<const float4*>(qr);           \
            const float4 a1 = *reinterpret_cast<const float4*>(qr + 4);       \
            const float4 a2 = *reinterpret_cast<const float4*>(qr + 8);       \
            const float4 a3 = *reinterpret_cast<const float4*>(qr + 12);      \
            const float aL  = qr[16];                                         \
            float u0 = at[0] * a0.x, u1 = at[1] * a0.y;                       \
            float u2 = at[2] * a0.z, u3 = at[3] * a0.w;                       \
            u0 = fmaf(at[4],  a1.x, u0); u1 = fmaf(at[5],  a1.y, u1);         \
            u2 = fmaf(at[6],  a1.z, u2); u3 = fmaf(at[7],  a1.w, u3);         \
            u0 = fmaf(at[8],  a2.x, u0); u1 = fmaf(at[9],  a2.y, u1);         \
            u2 = fmaf(at[10], a2.z, u2); u3 = fmaf(at[11], a2.w, u3);         \
            u0 = fmaf(at[12], a3.x, u0); u1 = fmaf(at[13], a3.y, u1);         \
            u2 = fmaf(at[14], a3.z, u2); u3 = fmaf(at[15], a3.w, u3);         \
            u0 = fmaf(at[16], aL,   u0);                                      \
            o[jj] = (u0 + u1) + (u2 + u3);                                    \
        }                                                                     \
        if (act) {                                                            \
            _Pragma("unroll")                                                 \
            for (int jj = 0; jj < 6; ++jj)                                    \
                QT[DST][j0 + jj][i] = e_ * o[jj];                             \
        }                                                                     \
        emv = env_;                                                           \
    }

    for (int pp = 0; pp < (trips >> 1); ++pp) {
        QSTEP(0, 1, t)
        QSTEP(1, 0, t + 1)
        t += 2;
        const float q00 = QT[0][0][0];
        const int E = (int)((__float_as_uint(q00) >> 23) & 0xff) - 127;
        Mi += E;
        psc = __builtin_amdgcn_ldexpf(1.f, -E);
    }
    int sbuf = 0;
    if (trips & 1) { QSTEP(0, 1, t) sbuf = 1; }
#undef QSTEP

    if (act) {
        float* dst = ws + (size_t)bs * QST + i * 20;
#pragma unroll
        for (int jj = 0; jj < 6; ++jj) {
            const int j = j0 + jj;
            if (j < 17) dst[j] = psc * QT[sbuf][j][i];
        }
    }
    if (l == 0) ws[(size_t)bs * QST + 340] = (float)Mi;
}

// ===========================================================================
// Kernel 2b: combine — UNCHANGED from R12.
// ===========================================================================
__device__ __forceinline__ float bcast(float v, int i) {
    return __uint_as_float(__builtin_amdgcn_readlane(__float_as_uint(v), i));
}

__global__ __launch_bounds__(64) void crf_combine_kernel(const float* __restrict__ emis,
                                                         const float* __restrict__ st_,
                                                         const float* __restrict__ en_,
                                                         const float* __restrict__ tr_,
                                                         const int* __restrict__ labels,
                                                         const int* __restrict__ mask,
                                                         const float* __restrict__ ws,
                                                         float* __restrict__ llh) {
    const int b = blockIdx.x;
    const int l = threadIdx.x;
    const float* eb = emis + (size_t)b * TT * NL;
    const int*   lb = labels + b * TT;

    int lenp = 0;
#pragma unroll
    for (int m = 0; m < 8; ++m) lenp += (mask[b * TT + l + 64 * m] != 0);
#pragma unroll
    for (int off = 32; off; off >>= 1) lenp += __shfl_down(lenp, off);
    const int len = __shfl(lenp, 0);

    float np = 0.f;
#pragma unroll
    for (int m = 0; m < 8; ++m) {
        const int t = l + 64 * m;
        int tag = lb[t]; if ((unsigned)tag >= NL) tag = 0;
        if (t < len) {
            if (t == 0) {
                np += st_[tag] + eb[tag];
            } else {
                int tp = lb[t - 1]; if ((unsigned)tp >= NL) tp = 0;
                np += tr_[tp * NL + tag] + eb[t * NL + tag];
            }
            if (t == len - 1) np += en_[tag];
        }
    }
#pragma unroll
    for (int off = 32; off; off >>= 1) np += __shfl_down(np, off);
    const float num = __shfl(np, 0);

    const bool act = (l < NL);
    const int  j   = act ? l : 0;

    float p  = act ? __expf(st_[j] + eb[j]) : 0.f;
    int   Mi = 0;

    for (int s = 0; s < SEG; ++s) {
        const float* qs = ws + (size_t)(b * SEG + s) * QST;
        const float* qr = qs + j * 20;
        const float4 a0 = *reinterpret_cast<const float4*>(qr);
        const float4 a1 = *reinterpret_cast<const float4*>(qr + 4);
        const float4 a2 = *reinterpret_cast<const float4*>(qr + 8);
        const float4 a3 = *reinterpret_cast<const float4*>(qr + 12);
        const float  aL = qr[16];
        const float  Msc = qs[340];

        float u0 = a0.x * bcast(p, 0),  u1 = a0.y * bcast(p, 1);
        float u2 = a0.z * bcast(p, 2),  u3 = a0.w * bcast(p, 3);
        u0 = fmaf(a1.x, bcast(p, 4),  u0); u1 = fmaf(a1.y, bcast(p, 5),  u1);
        u2 = fmaf(a1.z, bcast(p, 6),  u2); u3 = fmaf(a1.w, bcast(p, 7),  u3);
        u0 = fmaf(a2.x, bcast(p, 8),  u0); u1 = fmaf(a2.y, bcast(p, 9),  u1);
        u2 = fmaf(a2.z, bcast(p, 10), u2); u3 = fmaf(a2.w, bcast(p, 11), u3);
        u0 = fmaf(a3.x, bcast(p, 12), u0); u1 = fmaf(a3.y, bcast(p, 13), u1);
        u2 = fmaf(a3.z, bcast(p, 14), u2); u3 = fmaf(a3.w, bcast(p, 15), u3);
        u0 = fmaf(aL,   bcast(p, 16), u0);
        p = act ? ((u0 + u1) + (u2 + u3)) : 0.f;
        Mi += (int)Msc;

        const unsigned pb = (unsigned)__builtin_amdgcn_readlane((int)__float_as_uint(p), 0);
        const int e = (int)((pb >> 23) & 0xff) - 127;
        Mi += e;
        p = __builtin_amdgcn_ldexpf(p, -e);
    }

    float v = act ? p * __expf(en_[j]) : 0.f;
#pragma unroll
    for (int off = 32; off; off >>= 1) v += __shfl_down(v, off);

    if (l == 0) {
        const float denom = (float)Mi * 0.6931471805599453f + __logf(v);
        llh[b] = num - denom;
    }
}

// ===========================================================================
// Kernel 3: loss = -mean(llh)
// ===========================================================================
__global__ __launch_bounds__(64) void loss_kernel(const float* __restrict__ llh,
                                                  float* __restrict__ loss) {
    float v = llh[threadIdx.x];
#pragma unroll
    for (int off = 32; off; off >>= 1) v += __shfl_down(v, off);
    if (threadIdx.x == 0) loss[0] = -(v * (1.0f / BB));
}

// ===========================================================================
extern "C" void kernel_launch(void* const* d_in, const int* in_sizes, int n_in,
                              void* d_out, int out_size, void* d_ws, size_t ws_size,
                              hipStream_t stream) {
    const float* outputs = (const float*)d_in[0];
    const float* fc_w    = (const float*)d_in[1];
    const float* fc_b    = (const float*)d_in[2];
    const float* start_t = (const float*)d_in[3];
    const float* end_t   = (const float*)d_in[4];
    const float* trans   = (const float*)d_in[5];
    const int*   labels  = (const int*)d_in[6];
    const int*   mask    = (const int*)d_in[7];

    float* emis = (float*)d_out;
    float* loss = emis + (size_t)BB * TT * NL;
    float* ws   = (float*)d_ws;
    float* llh  = ws + (size_t)BB * SEG * QST;

    emis_kernel<<<(BB * TT) / 16, 256, 0, stream>>>(outputs, fc_w, fc_b, emis);
    crf_scan_kernel<<<BB * SEG, 64, 0, stream>>>(emis, trans, mask, ws);
    crf_combine_kernel<<<BB, 64, 0, stream>>>(emis, start_t, end_t, trans,
                                              labels, mask, ws, llh);
    loss_kernel<<<1, 64, 0, stream>>>(llh, loss);
}

// Round 15
// 67.485 us; speedup vs baseline: 1.3273x; 1.3273x over previous
//
#include <hip/hip_runtime.h>

#define HID 768
#define NL  17
#define BB  64
#define TT  512

// ---- CRF scan geometry (unchanged from R12) ----
#define SEG  16
#define SLEN 32
#define QST  352

typedef __attribute__((ext_vector_type(8))) short bf16x8;
typedef __attribute__((ext_vector_type(4))) float f32x4;

// v_cvt_pk_bf16_f32: dst.lo16 = bf16(a) RNE, dst.hi16 = bf16(b)
__device__ __forceinline__ unsigned cvtpk(float a, float b) {
    unsigned r;
    asm("v_cvt_pk_bf16_f32 %0, %1, %2" : "=v"(r) : "v"(a), "v"(b));
    return r;
}

// ===========================================================================
// Kernel 1: emissions = outputs @ fc_w^T + fc_b   (32768x768 @ 768^T x 17)
// R14 lesson: per-lane dot products replicate w through L1 (64B/clk) or LDS
// (34 ds_read/136 FMA) — every structure bottoms at ~55-60us. MFMA consumes
// fragments with no replication. Split-precision: x ~ xh+xl (bf16 RNE),
// w ~ wh+wl; x.w ~ xh.wh + xh.wl + xl.wh (err ~2^-16). Per wave: one 16-row
// M-tile, 24 K-steps of {2 coalesced dwordx4 x-loads, 6 cvt_pk, 4 ds_read
// B-frags, 6 mfma_f32_16x16x32_bf16}. w palette bf16 hi/lo in LDS once per
// block (54.6KB; col stride 776 shorts -> 2-way bank alias = free). No
// barriers in loop, nothing for the compiler to collapse. 8 waves/CU.
// Frag layout (m89-verified family): A row=l&15, k=(l>>4)*8+j; B col=l&15,
// k=(l>>4)*8+j; C/D col=l&15, row=(l>>4)*4+reg.
// ===========================================================================
__global__ __launch_bounds__(256) void emis_kernel(const float* __restrict__ x,
                                                   const float* __restrict__ w,
                                                   const float* __restrict__ bias,
                                                   float* __restrict__ y) {
    __shared__ unsigned short WP[2][18][776];   // [hi/lo][col (17=zeros)][k]

    const int tid = threadIdx.x;

    // ---- stage w as bf16 hi/lo palette (once per block) ----
    for (int c = 0; c < 17; ++c) {
        for (int e = tid; e < 768; e += 256) {
            const float f = w[c * HID + e];
            const unsigned u = __float_as_uint(f);
            const unsigned hb = (u + 0x7FFFu + ((u >> 16) & 1u)) >> 16;
            const float d = f - __uint_as_float(hb << 16);
            const unsigned ud = __float_as_uint(d);
            const unsigned lb = (ud + 0x7FFFu + ((ud >> 16) & 1u)) >> 16;
            WP[0][c][e] = (unsigned short)hb;
            WP[1][c][e] = (unsigned short)lb;
        }
    }
    for (int e = tid; e < 776; e += 256) { WP[0][17][e] = 0; WP[1][17][e] = 0; }
    __syncthreads();

    const int lane = tid & 63;
    const int c0   = lane & 15;                 // A row / B col / D col
    int c1 = 16 + c0; if (c1 > 17) c1 = 17;     // n-tile 1 col (>=17 -> zeros)
    const int kg   = (lane >> 4) * 8;           // k-group offset
    const int mtile = blockIdx.x * 4 + (tid >> 6);
    const float* xp = x + (size_t)(mtile * 16 + c0) * HID + kg;

    const unsigned short* pH0 = &WP[0][c0][kg];
    const unsigned short* pH1 = &WP[0][c1][kg];
    const unsigned short* pL0 = &WP[1][c0][kg];
    const unsigned short* pL1 = &WP[1][c1][kg];

    f32x4 acc0 = {0.f, 0.f, 0.f, 0.f};
    f32x4 acc1 = {0.f, 0.f, 0.f, 0.f};

    float4 q0 = *reinterpret_cast<const float4*>(xp);
    float4 q1 = *reinterpret_cast<const float4*>(xp + 4);

#pragma unroll 4
    for (int t = 0; t < 24; ++t) {
        const float4 a0 = q0, a1 = q1;
        if (t < 23) {                           // prefetch next K-step
            q0 = *reinterpret_cast<const float4*>(xp + 32 * (t + 1));
            q1 = *reinterpret_cast<const float4*>(xp + 32 * (t + 1) + 4);
        }

        // split x into hi/lo bf16 A-fragments (k = kg..kg+7 consecutive)
        union { unsigned u[4]; bf16x8 v; } H, L;
        H.u[0] = cvtpk(a0.x, a0.y);
        H.u[1] = cvtpk(a0.z, a0.w);
        H.u[2] = cvtpk(a1.x, a1.y);
        H.u[3] = cvtpk(a1.z, a1.w);
        L.u[0] = cvtpk(a0.x - __uint_as_float(H.u[0] << 16),
                       a0.y - __uint_as_float(H.u[0] & 0xFFFF0000u));
        L.u[1] = cvtpk(a0.z - __uint_as_float(H.u[1] << 16),
                       a0.w - __uint_as_float(H.u[1] & 0xFFFF0000u));
        L.u[2] = cvtpk(a1.x - __uint_as_float(H.u[2] << 16),
                       a1.y - __uint_as_float(H.u[2] & 0xFFFF0000u));
        L.u[3] = cvtpk(a1.z - __uint_as_float(H.u[3] << 16),
                       a1.w - __uint_as_float(H.u[3] & 0xFFFF0000u));

        const bf16x8 bh0 = *reinterpret_cast<const bf16x8*>(pH0 + 32 * t);
        const bf16x8 bh1 = *reinterpret_cast<const bf16x8*>(pH1 + 32 * t);
        const bf16x8 bl0 = *reinterpret_cast<const bf16x8*>(pL0 + 32 * t);
        const bf16x8 bl1 = *reinterpret_cast<const bf16x8*>(pL1 + 32 * t);

        acc0 = __builtin_amdgcn_mfma_f32_16x16x32_bf16(H.v, bh0, acc0, 0, 0, 0);
        acc0 = __builtin_amdgcn_mfma_f32_16x16x32_bf16(H.v, bl0, acc0, 0, 0, 0);
        acc0 = __builtin_amdgcn_mfma_f32_16x16x32_bf16(L.v, bh0, acc0, 0, 0, 0);
        acc1 = __builtin_amdgcn_mfma_f32_16x16x32_bf16(H.v, bh1, acc1, 0, 0, 0);
        acc1 = __builtin_amdgcn_mfma_f32_16x16x32_bf16(H.v, bl1, acc1, 0, 0, 0);
        acc1 = __builtin_amdgcn_mfma_f32_16x16x32_bf16(L.v, bh1, acc1, 0, 0, 0);
    }

    // ---- epilogue: D col = lane&15, row = (lane>>4)*4 + i ----
    const float bc  = bias[c0];
    const float b16 = bias[16];
    const int   rb  = mtile * 16 + (lane >> 4) * 4;
#pragma unroll
    for (int i = 0; i < 4; ++i) {
        const int row = rb + i;
        y[(size_t)row * NL + c0] = acc0[i] + bc;          // cols 0..15
        if (c0 == 0) y[(size_t)row * NL + 16] = acc1[i] + b16;  // col 16
    }
}

// ===========================================================================
// Kernel 2a: CRF segment scan — UNCHANGED from R12.
// ===========================================================================
__global__ __launch_bounds__(64) void crf_scan_kernel(const float* __restrict__ emis,
                                                      const float* __restrict__ tr_,
                                                      const int* __restrict__ mask,
                                                      float* __restrict__ ws) {
    __shared__ float QT[2][18][20];

    const int bs = blockIdx.x;
    const int b  = bs >> 4;
    const int s  = bs & 15;
    const int l  = threadIdx.x;
    const float* eb = emis + (size_t)b * TT * NL;

    int lenp = 0;
#pragma unroll
    for (int m = 0; m < 8; ++m) lenp += (mask[b * TT + l + 64 * m] != 0);
#pragma unroll
    for (int off = 32; off; off >>= 1) lenp += __shfl_down(lenp, off);
    const int len = __shfl(lenp, 0);

    const int t0    = 1 + SLEN * s;
    const int tend  = min(t0 + SLEN, len);
    const int trips = (tend > t0) ? (tend - t0) : 0;

    const bool act = (l < 51);
    const int  i   = act ? (l / 3) : 0;
    const int  m   = act ? (l - 3 * (l / 3)) : 0;
    const int  j0  = 6 * m;

    if (act) {
#pragma unroll
        for (int jj = 0; jj < 6; ++jj)
            QT[0][j0 + jj][i] = (i == j0 + jj) ? 1.f : 0.f;
    }

    float at[17];
#pragma unroll
    for (int k = 0; k < 17; ++k) at[k] = __expf(tr_[k * NL + i]);

    float psc = 1.f;
    int   Mi  = 0;
    float emv = (trips > 0) ? eb[t0 * NL + i] : 0.f;
    int   t   = t0;

#define QSTEP(SRC, DST, TCUR)                                                 \
    {                                                                         \
        const float e_ = __expf(emv) * psc;  psc = 1.f;                       \
        const int tn_ = ((TCUR) + 1 < tend) ? ((TCUR) + 1) : (TT - 1);        \
        const float env_ = eb[tn_ * NL + i];                                  \
        float o[6];                                                           \
        _Pragma("unroll")                                                     \
        for (int jj = 0; jj < 6; ++jj) {                                      \
            const float* qr = &QT[SRC][j0 + jj][0];                           \
            const float4 a0 = *reinterpret_cast<const float4*>(qr);           \
            const float4 a1 = *reinterpret_cast<const float4*>(qr + 4);       \
            const float4 a2 = *reinterpret_cast<const float4*>(qr + 8);       \
            const float4 a3 = *reinterpret_cast<const float4*>(qr + 12);      \
            const float aL  = qr[16];                                         \
            float u0 = at[0] * a0.x, u1 = at[1] * a0.y;                       \
            float u2 = at[2] * a0.z, u3 = at[3] * a0.w;                       \
            u0 = fmaf(at[4],  a1.x, u0); u1 = fmaf(at[5],  a1.y, u1);         \
            u2 = fmaf(at[6],  a1.z, u2); u3 = fmaf(at[7],  a1.w, u3);         \
            u0 = fmaf(at[8],  a2.x, u0); u1 = fmaf(at[9],  a2.y, u1);         \
            u2 = fmaf(at[10], a2.z, u2); u3 = fmaf(at[11], a2.w, u3);         \
            u0 = fmaf(at[12], a3.x, u0); u1 = fmaf(at[13], a3.y, u1);         \
            u2 = fmaf(at[14], a3.z, u2); u3 = fmaf(at[15], a3.w, u3);         \
            u0 = fmaf(at[16], aL,   u0);                                      \
            o[jj] = (u0 + u1) + (u2 + u3);                                    \
        }                                                                     \
        if (act) {                                                            \
            _Pragma("unroll")                                                 \
            for (int jj = 0; jj < 6; ++jj)                                    \
                QT[DST][j0 + jj][i] = e_ * o[jj];                             \
        }                                                                     \
        emv = env_;                                                           \
    }

    for (int pp = 0; pp < (trips >> 1); ++pp) {
        QSTEP(0, 1, t)
        QSTEP(1, 0, t + 1)
        t += 2;
        const float q00 = QT[0][0][0];
        const int E = (int)((__float_as_uint(q00) >> 23) & 0xff) - 127;
        Mi += E;
        psc = __builtin_amdgcn_ldexpf(1.f, -E);
    }
    int sbuf = 0;
    if (trips & 1) { QSTEP(0, 1, t) sbuf = 1; }
#undef QSTEP

    if (act) {
        float* dst = ws + (size_t)bs * QST + i * 20;
#pragma unroll
        for (int jj = 0; jj < 6; ++jj) {
            const int j = j0 + jj;
            if (j < 17) dst[j] = psc * QT[sbuf][j][i];
        }
    }
    if (l == 0) ws[(size_t)bs * QST + 340] = (float)Mi;
}

// ===========================================================================
// Kernel 2b: combine — UNCHANGED from R12.
// ===========================================================================
__device__ __forceinline__ float bcast(float v, int i) {
    return __uint_as_float(__builtin_amdgcn_readlane(__float_as_uint(v), i));
}

__global__ __launch_bounds__(64) void crf_combine_kernel(const float* __restrict__ emis,
                                                         const float* __restrict__ st_,
                                                         const float* __restrict__ en_,
                                                         const float* __restrict__ tr_,
                                                         const int* __restrict__ labels,
                                                         const int* __restrict__ mask,
                                                         const float* __restrict__ ws,
                                                         float* __restrict__ llh) {
    const int b = blockIdx.x;
    const int l = threadIdx.x;
    const float* eb = emis + (size_t)b * TT * NL;
    const int*   lb = labels + b * TT;

    int lenp = 0;
#pragma unroll
    for (int m = 0; m < 8; ++m) lenp += (mask[b * TT + l + 64 * m] != 0);
#pragma unroll
    for (int off = 32; off; off >>= 1) lenp += __shfl_down(lenp, off);
    const int len = __shfl(lenp, 0);

    float np = 0.f;
#pragma unroll
    for (int m = 0; m < 8; ++m) {
        const int t = l + 64 * m;
        int tag = lb[t]; if ((unsigned)tag >= NL) tag = 0;
        if (t < len) {
            if (t == 0) {
                np += st_[tag] + eb[tag];
            } else {
                int tp = lb[t - 1]; if ((unsigned)tp >= NL) tp = 0;
                np += tr_[tp * NL + tag] + eb[t * NL + tag];
            }
            if (t == len - 1) np += en_[tag];
        }
    }
#pragma unroll
    for (int off = 32; off; off >>= 1) np += __shfl_down(np, off);
    const float num = __shfl(np, 0);

    const bool act = (l < NL);
    const int  j   = act ? l : 0;

    float p  = act ? __expf(st_[j] + eb[j]) : 0.f;
    int   Mi = 0;

    for (int s = 0; s < SEG; ++s) {
        const float* qs = ws + (size_t)(b * SEG + s) * QST;
        const float* qr = qs + j * 20;
        const float4 a0 = *reinterpret_cast<const float4*>(qr);
        const float4 a1 = *reinterpret_cast<const float4*>(qr + 4);
        const float4 a2 = *reinterpret_cast<const float4*>(qr + 8);
        const float4 a3 = *reinterpret_cast<const float4*>(qr + 12);
        const float  aL = qr[16];
        const float  Msc = qs[340];

        float u0 = a0.x * bcast(p, 0),  u1 = a0.y * bcast(p, 1);
        float u2 = a0.z * bcast(p, 2),  u3 = a0.w * bcast(p, 3);
        u0 = fmaf(a1.x, bcast(p, 4),  u0); u1 = fmaf(a1.y, bcast(p, 5),  u1);
        u2 = fmaf(a1.z, bcast(p, 6),  u2); u3 = fmaf(a1.w, bcast(p, 7),  u3);
        u0 = fmaf(a2.x, bcast(p, 8),  u0); u1 = fmaf(a2.y, bcast(p, 9),  u1);
        u2 = fmaf(a2.z, bcast(p, 10), u2); u3 = fmaf(a2.w, bcast(p, 11), u3);
        u0 = fmaf(a3.x, bcast(p, 12), u0); u1 = fmaf(a3.y, bcast(p, 13), u1);
        u2 = fmaf(a3.z, bcast(p, 14), u2); u3 = fmaf(a3.w, bcast(p, 15), u3);
        u0 = fmaf(aL,   bcast(p, 16), u0);
        p = act ? ((u0 + u1) + (u2 + u3)) : 0.f;
        Mi += (int)Msc;

        const unsigned pb = (unsigned)__builtin_amdgcn_readlane((int)__float_as_uint(p), 0);
        const int e = (int)((pb >> 23) & 0xff) - 127;
        Mi += e;
        p = __builtin_amdgcn_ldexpf(p, -e);
    }

    float v = act ? p * __expf(en_[j]) : 0.f;
#pragma unroll
    for (int off = 32; off; off >>= 1) v += __shfl_down(v, off);

    if (l == 0) {
        const float denom = (float)Mi * 0.6931471805599453f + __logf(v);
        llh[b] = num - denom;
    }
}

// ===========================================================================
// Kernel 3: loss = -mean(llh)
// ===========================================================================
__global__ __launch_bounds__(64) void loss_kernel(const float* __restrict__ llh,
                                                  float* __restrict__ loss) {
    float v = llh[threadIdx.x];
#pragma unroll
    for (int off = 32; off; off >>= 1) v += __shfl_down(v, off);
    if (threadIdx.x == 0) loss[0] = -(v * (1.0f / BB));
}

// ===========================================================================
extern "C" void kernel_launch(void* const* d_in, const int* in_sizes, int n_in,
                              void* d_out, int out_size, void* d_ws, size_t ws_size,
                              hipStream_t stream) {
    const float* outputs = (const float*)d_in[0];
    const float* fc_w    = (const float*)d_in[1];
    const float* fc_b    = (const float*)d_in[2];
    const float* start_t = (const float*)d_in[3];
    const float* end_t   = (const float*)d_in[4];
    const float* trans   = (const float*)d_in[5];
    const int*   labels  = (const int*)d_in[6];
    const int*   mask    = (const int*)d_in[7];

    float* emis = (float*)d_out;
    float* loss = emis + (size_t)BB * TT * NL;
    float* ws   = (float*)d_ws;
    float* llh  = ws + (size_t)BB * SEG * QST;

    emis_kernel<<<(BB * TT) / 64, 256, 0, stream>>>(outputs, fc_w, fc_b, emis);
    crf_scan_kernel<<<BB * SEG, 64, 0, stream>>>(emis, trans, mask, ws);
    crf_combine_kernel<<<BB, 64, 0, stream>>>(emis, start_t, end_t, trans,
                                              labels, mask, ws, llh);
    loss_kernel<<<1, 64, 0, stream>>>(llh, loss);
}

// Round 16
// 56.410 us; speedup vs baseline: 1.5879x; 1.1963x over previous
//
#include <hip/hip_runtime.h>

#define HID 768
#define NL  17
#define BB  64
#define TT  512

// ---- CRF scan geometry (unchanged from R12) ----
#define SEG  16
#define SLEN 32
#define QST  352

typedef __attribute__((ext_vector_type(8))) short bf16x8;
typedef __attribute__((ext_vector_type(4))) float f32x4;

// v_cvt_pk_bf16_f32: dst.lo16 = bf16(a) RNE, dst.hi16 = bf16(b)
__device__ __forceinline__ unsigned cvtpk(float a, float b) {
    unsigned r;
    asm("v_cvt_pk_bf16_f32 %0, %1, %2" : "=v"(r) : "v"(a), "v"(b));
    return r;
}

// ===========================================================================
// Kernel 1: emissions = outputs @ fc_w^T + fc_b   (32768x768 @ 768^T x 17)
// R15 post-mortem: every variant stalled at ~60us because in-flight depth per
// wave was ~1 iteration (vmcnt(0) each step -> ~2KB x tiny duty -> ~1TB/s by
// Little's law; fillBuffer WRITES hit 7TB/s at 9% occupancy because writes
// have no latency to hide). Fix: 4-deep NAMED-register load rotation, fully
// unrolled 24-step loop (static indices, rule #20). Consuming the oldest
// pair waits vmcnt(6) by register deps alone: 3 pairs = 6KB/wave stay in
// flight THROUGH every stall; 8 waves/CU -> ~50KB/CU >> 9.2KB needed for
// 6.3TB/s. MFMA split-precision (x~xh+xl bf16; acc = xh.wh+xh.wl+xl.wh,
// err ~2^-16) with w as bf16 hi/lo LDS palette — R15-verified layouts.
// ===========================================================================
__global__ __launch_bounds__(256) void emis_kernel(const float* __restrict__ x,
                                                   const float* __restrict__ w,
                                                   const float* __restrict__ bias,
                                                   float* __restrict__ y) {
    __shared__ unsigned short WP[2][18][776];   // [hi/lo][col (17=zeros)][k]

    const int tid = threadIdx.x;

    // ---- stage w as bf16 hi/lo palette (vectorized, deep-issued) ----
    for (int e = tid; e < 776; e += 256) { WP[0][17][e] = 0; WP[1][17][e] = 0; }
#pragma unroll
    for (int j = 0; j < 13; ++j) {
        const int g4 = tid + 256 * j;           // float4 granule 0..3263
        if (g4 < 3264) {
            const float4 f = *reinterpret_cast<const float4*>(w + 4 * g4);
            const int col = g4 / 192;           // 192 granules per row
            const int e   = (g4 - col * 192) * 4;
            const unsigned h0 = cvtpk(f.x, f.y);
            const unsigned h1 = cvtpk(f.z, f.w);
            const unsigned l0 = cvtpk(f.x - __uint_as_float(h0 << 16),
                                      f.y - __uint_as_float(h0 & 0xFFFF0000u));
            const unsigned l1 = cvtpk(f.z - __uint_as_float(h1 << 16),
                                      f.w - __uint_as_float(h1 & 0xFFFF0000u));
            uint2 hv; hv.x = h0; hv.y = h1;
            uint2 lv; lv.x = l0; lv.y = l1;
            *reinterpret_cast<uint2*>(&WP[0][col][e]) = hv;
            *reinterpret_cast<uint2*>(&WP[1][col][e]) = lv;
        }
    }
    __syncthreads();

    const int lane = tid & 63;
    const int c0   = lane & 15;                 // A row / B col / D col
    int c1 = 16 + c0; if (c1 > 17) c1 = 17;     // n-tile 1 col (>=17 -> zeros)
    const int kg   = (lane >> 4) * 8;           // k-group offset
    const int mtile = blockIdx.x * 4 + (tid >> 6);
    const float* xp = x + (size_t)(mtile * 16 + c0) * HID + kg;

    const unsigned short* pH0 = &WP[0][c0][kg];
    const unsigned short* pH1 = &WP[0][c1][kg];
    const unsigned short* pL0 = &WP[1][c0][kg];
    const unsigned short* pL1 = &WP[1][c1][kg];

    f32x4 acc0 = {0.f, 0.f, 0.f, 0.f};
    f32x4 acc1 = {0.f, 0.f, 0.f, 0.f};

#define LDX(T)  (*reinterpret_cast<const float4*>(xp + 32 * (T)))
#define LDX4(T) (*reinterpret_cast<const float4*>(xp + 32 * (T) + 4))

#define XSTEP(Q0, Q1, T)                                                      \
    {                                                                         \
        union { unsigned u[4]; bf16x8 v; } H_, L_;                            \
        H_.u[0] = cvtpk(Q0.x, Q0.y);                                          \
        H_.u[1] = cvtpk(Q0.z, Q0.w);                                          \
        H_.u[2] = cvtpk(Q1.x, Q1.y);                                          \
        H_.u[3] = cvtpk(Q1.z, Q1.w);                                          \
        L_.u[0] = cvtpk(Q0.x - __uint_as_float(H_.u[0] << 16),                \
                        Q0.y - __uint_as_float(H_.u[0] & 0xFFFF0000u));       \
        L_.u[1] = cvtpk(Q0.z - __uint_as_float(H_.u[1] << 16),                \
                        Q0.w - __uint_as_float(H_.u[1] & 0xFFFF0000u));       \
        L_.u[2] = cvtpk(Q1.x - __uint_as_float(H_.u[2] << 16),                \
                        Q1.y - __uint_as_float(H_.u[2] & 0xFFFF0000u));       \
        L_.u[3] = cvtpk(Q1.z - __uint_as_float(H_.u[3] << 16),                \
                        Q1.w - __uint_as_float(H_.u[3] & 0xFFFF0000u));       \
        const bf16x8 bh0 = *reinterpret_cast<const bf16x8*>(pH0 + 32 * (T));  \
        const bf16x8 bh1 = *reinterpret_cast<const bf16x8*>(pH1 + 32 * (T));  \
        const bf16x8 bl0 = *reinterpret_cast<const bf16x8*>(pL0 + 32 * (T));  \
        const bf16x8 bl1 = *reinterpret_cast<const bf16x8*>(pL1 + 32 * (T));  \
        acc0 = __builtin_amdgcn_mfma_f32_16x16x32_bf16(H_.v, bh0, acc0, 0, 0, 0); \
        acc0 = __builtin_amdgcn_mfma_f32_16x16x32_bf16(H_.v, bl0, acc0, 0, 0, 0); \
        acc0 = __builtin_amdgcn_mfma_f32_16x16x32_bf16(L_.v, bh0, acc0, 0, 0, 0); \
        acc1 = __builtin_amdgcn_mfma_f32_16x16x32_bf16(H_.v, bh1, acc1, 0, 0, 0); \
        acc1 = __builtin_amdgcn_mfma_f32_16x16x32_bf16(H_.v, bl1, acc1, 0, 0, 0); \
        acc1 = __builtin_amdgcn_mfma_f32_16x16x32_bf16(L_.v, bh1, acc1, 0, 0, 0); \
    }

    // 4-deep rotation: qA..qD named pairs, 6KB/wave in flight at every stall
    float4 qA0 = LDX(0), qA1 = LDX4(0);
    float4 qB0 = LDX(1), qB1 = LDX4(1);
    float4 qC0 = LDX(2), qC1 = LDX4(2);
    float4 qD0 = LDX(3), qD1 = LDX4(3);

#pragma unroll
    for (int t = 0; t < 24; t += 4) {
        XSTEP(qA0, qA1, t)
        if (t + 4 < 24) { qA0 = LDX(t + 4); qA1 = LDX4(t + 4); }
        XSTEP(qB0, qB1, t + 1)
        if (t + 5 < 24) { qB0 = LDX(t + 5); qB1 = LDX4(t + 5); }
        XSTEP(qC0, qC1, t + 2)
        if (t + 6 < 24) { qC0 = LDX(t + 6); qC1 = LDX4(t + 6); }
        XSTEP(qD0, qD1, t + 3)
        if (t + 7 < 24) { qD0 = LDX(t + 7); qD1 = LDX4(t + 7); }
    }
#undef XSTEP
#undef LDX
#undef LDX4

    // ---- epilogue: D col = lane&15, row = (lane>>4)*4 + i ----
    const float bc  = bias[c0];
    const float b16 = bias[16];
    const int   rb  = mtile * 16 + (lane >> 4) * 4;
#pragma unroll
    for (int i = 0; i < 4; ++i) {
        const int row = rb + i;
        y[(size_t)row * NL + c0] = acc0[i] + bc;                // cols 0..15
        if (c0 == 0) y[(size_t)row * NL + 16] = acc1[i] + b16;  // col 16
    }
}

// ===========================================================================
// Kernel 2a: CRF segment scan — UNCHANGED from R12.
// ===========================================================================
__global__ __launch_bounds__(64) void crf_scan_kernel(const float* __restrict__ emis,
                                                      const float* __restrict__ tr_,
                                                      const int* __restrict__ mask,
                                                      float* __restrict__ ws) {
    __shared__ float QT[2][18][20];

    const int bs = blockIdx.x;
    const int b  = bs >> 4;
    const int s  = bs & 15;
    const int l  = threadIdx.x;
    const float* eb = emis + (size_t)b * TT * NL;

    int lenp = 0;
#pragma unroll
    for (int m = 0; m < 8; ++m) lenp += (mask[b * TT + l + 64 * m] != 0);
#pragma unroll
    for (int off = 32; off; off >>= 1) lenp += __shfl_down(lenp, off);
    const int len = __shfl(lenp, 0);

    const int t0    = 1 + SLEN * s;
    const int tend  = min(t0 + SLEN, len);
    const int trips = (tend > t0) ? (tend - t0) : 0;

    const bool act = (l < 51);
    const int  i   = act ? (l / 3) : 0;
    const int  m   = act ? (l - 3 * (l / 3)) : 0;
    const int  j0  = 6 * m;

    if (act) {
#pragma unroll
        for (int jj = 0; jj < 6; ++jj)
            QT[0][j0 + jj][i] = (i == j0 + jj) ? 1.f : 0.f;
    }

    float at[17];
#pragma unroll
    for (int k = 0; k < 17; ++k) at[k] = __expf(tr_[k * NL + i]);

    float psc = 1.f;
    int   Mi  = 0;
    float emv = (trips > 0) ? eb[t0 * NL + i] : 0.f;
    int   t   = t0;

#define QSTEP(SRC, DST, TCUR)                                                 \
    {                                                                         \
        const float e_ = __expf(emv) * psc;  psc = 1.f;                       \
        const int tn_ = ((TCUR) + 1 < tend) ? ((TCUR) + 1) : (TT - 1);        \
        const float env_ = eb[tn_ * NL + i];                                  \
        float o[6];                                                           \
        _Pragma("unroll")                                                     \
        for (int jj = 0; jj < 6; ++jj) {                                      \
            const float* qr = &QT[SRC][j0 + jj][0];                           \
            const float4 a0 = *reinterpret_cast<const float4*>(qr);           \
            const float4 a1 = *reinterpret_cast<const float4*>(qr + 4);       \
            const float4 a2 = *reinterpret_cast<const float4*>(qr + 8);       \
            const float4 a3 = *reinterpret_cast<const float4*>(qr + 12);      \
            const float aL  = qr[16];                                         \
            float u0 = at[0] * a0.x, u1 = at[1] * a0.y;                       \
            float u2 = at[2] * a0.z, u3 = at[3] * a0.w;                       \
            u0 = fmaf(at[4],  a1.x, u0); u1 = fmaf(at[5],  a1.y, u1);         \
            u2 = fmaf(at[6],  a1.z, u2); u3 = fmaf(at[7],  a1.w, u3);         \
            u0 = fmaf(at[8],  a2.x, u0); u1 = fmaf(at[9],  a2.y, u1);         \
            u2 = fmaf(at[10], a2.z, u2); u3 = fmaf(at[11], a2.w, u3);         \
            u0 = fmaf(at[12], a3.x, u0); u1 = fmaf(at[13], a3.y, u1);         \
            u2 = fmaf(at[14], a3.z, u2); u3 = fmaf(at[15], a3.w, u3);         \
            u0 = fmaf(at[16], aL,   u0);                                      \
            o[jj] = (u0 + u1) + (u2 + u3);                                    \
        }                                                                     \
        if (act) {                                                            \
            _Pragma("unroll")                                                 \
            for (int jj = 0; jj < 6; ++jj)                                    \
                QT[DST][j0 + jj][i] = e_ * o[jj];                             \
        }                                                                     \
        emv = env_;                                                           \
    }

    for (int pp = 0; pp < (trips >> 1); ++pp) {
        QSTEP(0, 1, t)
        QSTEP(1, 0, t + 1)
        t += 2;
        const float q00 = QT[0][0][0];
        const int E = (int)((__float_as_uint(q00) >> 23) & 0xff) - 127;
        Mi += E;
        psc = __builtin_amdgcn_ldexpf(1.f, -E);
    }
    int sbuf = 0;
    if (trips & 1) { QSTEP(0, 1, t) sbuf = 1; }
#undef QSTEP

    if (act) {
        float* dst = ws + (size_t)bs * QST + i * 20;
#pragma unroll
        for (int jj = 0; jj < 6; ++jj) {
            const int j = j0 + jj;
            if (j < 17) dst[j] = psc * QT[sbuf][j][i];
        }
    }
    if (l == 0) ws[(size_t)bs * QST + 340] = (float)Mi;
}

// ===========================================================================
// Kernel 2b: combine — UNCHANGED from R12.
// ===========================================================================
__device__ __forceinline__ float bcast(float v, int i) {
    return __uint_as_float(__builtin_amdgcn_readlane(__float_as_uint(v), i));
}

__global__ __launch_bounds__(64) void crf_combine_kernel(const float* __restrict__ emis,
                                                         const float* __restrict__ st_,
                                                         const float* __restrict__ en_,
                                                         const float* __restrict__ tr_,
                                                         const int* __restrict__ labels,
                                                         const int* __restrict__ mask,
                                                         const float* __restrict__ ws,
                                                         float* __restrict__ llh) {
    const int b = blockIdx.x;
    const int l = threadIdx.x;
    const float* eb = emis + (size_t)b * TT * NL;
    const int*   lb = labels + b * TT;

    int lenp = 0;
#pragma unroll
    for (int m = 0; m < 8; ++m) lenp += (mask[b * TT + l + 64 * m] != 0);
#pragma unroll
    for (int off = 32; off; off >>= 1) lenp += __shfl_down(lenp, off);
    const int len = __shfl(lenp, 0);

    float np = 0.f;
#pragma unroll
    for (int m = 0; m < 8; ++m) {
        const int t = l + 64 * m;
        int tag = lb[t]; if ((unsigned)tag >= NL) tag = 0;
        if (t < len) {
            if (t == 0) {
                np += st_[tag] + eb[tag];
            } else {
                int tp = lb[t - 1]; if ((unsigned)tp >= NL) tp = 0;
                np += tr_[tp * NL + tag] + eb[t * NL + tag];
            }
            if (t == len - 1) np += en_[tag];
        }
    }
#pragma unroll
    for (int off = 32; off; off >>= 1) np += __shfl_down(np, off);
    const float num = __shfl(np, 0);

    const bool act = (l < NL);
    const int  j   = act ? l : 0;

    float p  = act ? __expf(st_[j] + eb[j]) : 0.f;
    int   Mi = 0;

    for (int s = 0; s < SEG; ++s) {
        const float* qs = ws + (size_t)(b * SEG + s) * QST;
        const float* qr = qs + j * 20;
        const float4 a0 = *reinterpret_cast<const float4*>(qr);
        const float4 a1 = *reinterpret_cast<const float4*>(qr + 4);
        const float4 a2 = *reinterpret_cast<const float4*>(qr + 8);
        const float4 a3 = *reinterpret_cast<const float4*>(qr + 12);
        const float  aL = qr[16];
        const float  Msc = qs[340];

        float u0 = a0.x * bcast(p, 0),  u1 = a0.y * bcast(p, 1);
        float u2 = a0.z * bcast(p, 2),  u3 = a0.w * bcast(p, 3);
        u0 = fmaf(a1.x, bcast(p, 4),  u0); u1 = fmaf(a1.y, bcast(p, 5),  u1);
        u2 = fmaf(a1.z, bcast(p, 6),  u2); u3 = fmaf(a1.w, bcast(p, 7),  u3);
        u0 = fmaf(a2.x, bcast(p, 8),  u0); u1 = fmaf(a2.y, bcast(p, 9),  u1);
        u2 = fmaf(a2.z, bcast(p, 10), u2); u3 = fmaf(a2.w, bcast(p, 11), u3);
        u0 = fmaf(a3.x, bcast(p, 12), u0); u1 = fmaf(a3.y, bcast(p, 13), u1);
        u2 = fmaf(a3.z, bcast(p, 14), u2); u3 = fmaf(a3.w, bcast(p, 15), u3);
        u0 = fmaf(aL,   bcast(p, 16), u0);
        p = act ? ((u0 + u1) + (u2 + u3)) : 0.f;
        Mi += (int)Msc;

        const unsigned pb = (unsigned)__builtin_amdgcn_readlane((int)__float_as_uint(p), 0);
        const int e = (int)((pb >> 23) & 0xff) - 127;
        Mi += e;
        p = __builtin_amdgcn_ldexpf(p, -e);
    }

    float v = act ? p * __expf(en_[j]) : 0.f;
#pragma unroll
    for (int off = 32; off; off >>= 1) v += __shfl_down(v, off);

    if (l == 0) {
        const float denom = (float)Mi * 0.6931471805599453f + __logf(v);
        llh[b] = num - denom;
    }
}

// ===========================================================================
// Kernel 3: loss = -mean(llh)
// ===========================================================================
__global__ __launch_bounds__(64) void loss_kernel(const float* __restrict__ llh,
                                                  float* __restrict__ loss) {
    float v = llh[threadIdx.x];
#pragma unroll
    for (int off = 32; off; off >>= 1) v += __shfl_down(v, off);
    if (threadIdx.x == 0) loss[0] = -(v * (1.0f / BB));
}

// ===========================================================================
extern "C" void kernel_launch(void* const* d_in, const int* in_sizes, int n_in,
                              void* d_out, int out_size, void* d_ws, size_t ws_size,
                              hipStream_t stream) {
    const float* outputs = (const float*)d_in[0];
    const float* fc_w    = (const float*)d_in[1];
    const float* fc_b    = (const float*)d_in[2];
    const float* start_t = (const float*)d_in[3];
    const float* end_t   = (const float*)d_in[4];
    const float* trans   = (const float*)d_in[5];
    const int*   labels  = (const int*)d_in[6];
    const int*   mask    = (const int*)d_in[7];

    float* emis = (float*)d_out;
    float* loss = emis + (size_t)BB * TT * NL;
    float* ws   = (float*)d_ws;
    float* llh  = ws + (size_t)BB * SEG * QST;

    emis_kernel<<<(BB * TT) / 64, 256, 0, stream>>>(outputs, fc_w, fc_b, emis);
    crf_scan_kernel<<<BB * SEG, 64, 0, stream>>>(emis, trans, mask, ws);
    crf_combine_kernel<<<BB, 64, 0, stream>>>(emis, start_t, end_t, trans,
                                              labels, mask, ws, llh);
    loss_kernel<<<1, 64, 0, stream>>>(llh, loss);
}